// Round 2
// baseline (308.665 us; speedup 1.0000x reference)
//
#include <hip/hip_runtime.h>

// dims: S=128, E=256 -> 32768 pairs; H=20, D=64, A=64, NH=8
constexpr float TEMP = 2.5f;    // H / sqrt(A) = 20/8
constexpr float NEGV = -1e9f;

// ---- workspace layout (floats) ----
constexpr int M_OFF = 0;        // M[8][64][64]  (pre-scaled by TEMP)
constexpr int K_OFF = 32768;    // k[8][64]
constexpr int P_OFF = 33280;    // p[8][64]
constexpr int Q_OFF = 33792;    // q[8]

// ---- main-kernel LDS layout (floats) ----
constexpr int HS_OFF  = 0;      // hs[8][20][66] = 10560 ; later y[8][8][66] (4224)
constexpr int V_OFF   = 10560;  // V/wv [8][520] flat n*64+d              (4160)
constexpr int ATT_OFF = 14720;  // attn[8][20][10]                        (1600)
constexpr int C_OFF   = 16320;  // c[8 pairs][8 heads]                    (64)
constexpr int LEN_OFF = 16384;  // len[8]                                 (8)
constexpr int LDS_FL  = 16392;  // 65,568 B -> 2 blocks/CU (16 waves/CU)

// ============================================================
// prep: M[n][dp][d] = sum_a Wt[n][dp][a]*Ws[n][d][a];  k = Ws·bt;
//       p = Wt·bs;  q = bt·bs.  All scaled by TEMP.  (unchanged, verified)
// ============================================================
__global__ __launch_bounds__(256) void prep_kernel(
    const float* __restrict__ Wt, const float* __restrict__ bt,
    const float* __restrict__ Ws, const float* __restrict__ bs,
    float* __restrict__ ws) {
  __shared__ float WsL[64 * 65];
  __shared__ float WtL[16 * 65];
  const int t  = threadIdx.x;
  const int n  = blockIdx.x >> 2;
  const int q  = blockIdx.x & 3;
  const int dp0 = q * 16;
  const float* Wtn = Wt + n * 4096;
  const float* Wsn = Ws + n * 4096;
#pragma unroll
  for (int i = 0; i < 16; ++i) {
    const int idx = i * 256 + t;
    WsL[(idx >> 6) * 65 + (idx & 63)] = Wsn[idx];
  }
#pragma unroll
  for (int i = 0; i < 4; ++i) {
    const int idx = i * 256 + t;
    WtL[(idx >> 6) * 65 + (idx & 63)] = Wtn[dp0 * 64 + idx];
  }
  __syncthreads();
#pragma unroll
  for (int i = 0; i < 4; ++i) {
    const int idx = i * 256 + t;
    const int dpl = idx >> 6, d = idx & 63;
    const float* wtr = &WtL[dpl * 65];
    const float* wsr = &WsL[d * 65];
    float acc = 0.f;
#pragma unroll 8
    for (int a = 0; a < 64; ++a) acc += wtr[a] * wsr[a];
    ws[M_OFF + n * 4096 + (dp0 + dpl) * 64 + d] = acc * TEMP;
  }
  if (q == 0 && t < 64) {
    float acc = 0.f;
#pragma unroll 8
    for (int a = 0; a < 64; ++a) acc += WsL[t * 65 + a] * bt[n * 64 + a];
    ws[K_OFF + n * 64 + t] = acc * TEMP;
  }
  if (t >= 64 && t < 80) {
    const int r = t - 64;
    float acc = 0.f;
#pragma unroll 8
    for (int a = 0; a < 64; ++a) acc += WtL[r * 65 + a] * bs[n * 64 + a];
    ws[P_OFF + n * 64 + dp0 + r] = acc * TEMP;
  }
  if (q == 0 && t == 128) {
    float acc = 0.f;
    for (int a = 0; a < 64; ++a) acc += bt[n * 64 + a] * bs[n * 64 + a];
    ws[Q_OFF + n] = acc * TEMP;
  }
}

// ============================================================
// main: 8 pairs/block, 512 threads (8 waves), grid 4096.
// ============================================================
__global__ __launch_bounds__(512, 4) void attn_kernel(
    const float* __restrict__ ht_g, const float* __restrict__ hs_g,
    const int* __restrict__ len_g, const float* __restrict__ Wf,
    const float* __restrict__ bf, const float* __restrict__ wsp,
    float* __restrict__ out) {
  __shared__ float lds[LDS_FL];
  const int t    = threadIdx.x;
  const int lane = t & 63;
  const int w    = t >> 6;            // wave id 0..7
  const int pair0 = blockIdx.x * 8;

  // ---------- issue hs prefetch into registers (consumed after V phase) ----
  float4 hv[5];
  {
    const float4* hs4 = (const float4*)(hs_g + (size_t)pair0 * 1280);
#pragma unroll
    for (int i = 0; i < 5; ++i) hv[i] = hs4[i * 512 + t];
  }
  if (t < 8) lds[LEN_OFF + t] = (float)len_g[pair0 + t];

  // ---------- V phase: wave w = head n, lane = d, 8 pair-accumulators ------
  // V[p][n][d] = k[n][d] + sum_dp ht[p][dp] * M[n][dp][d]
  {
    const int n = w;
    const int d = lane;
    float acc[8];
    const float kv = wsp[K_OFF + n * 64 + d];
#pragma unroll
    for (int p = 0; p < 8; ++p) acc[p] = kv;
    const float* Mn  = &wsp[M_OFF + n * 4096];
    const float* htb = ht_g + (size_t)pair0 * 64;   // wave-uniform indexing
#pragma unroll 8
    for (int dp = 0; dp < 64; ++dp) {
      const float mv = Mn[dp * 64 + d];             // coalesced b32 (L2)
#pragma unroll
      for (int p = 0; p < 8; ++p)
        acc[p] = fmaf(htb[p * 64 + dp], mv, acc[p]); // scalar (SGPR) operand
    }
    float* vp = &lds[V_OFF + n * 64 + d];
#pragma unroll
    for (int p = 0; p < 8; ++p) vp[p * 520] = acc[p];  // stride-1, no conflict
  }

  // ---------- c[p][n] = q[n] + ht·p[n]  (8 lanes of each wave) ------------
  {
    const int n = w;
    if (lane < 8) {
      const float* htp = ht_g + (size_t)(pair0 + lane) * 64;
      float cacc = wsp[Q_OFF + n];
#pragma unroll 8
      for (int dp = 0; dp < 64; ++dp)
        cacc = fmaf(htp[dp], wsp[P_OFF + n * 64 + dp], cacc);
      lds[C_OFF + lane * 8 + n] = cacc;
    }
  }

  // ---------- write prefetched hs into LDS [8][20][66] --------------------
  {
#pragma unroll
    for (int i = 0; i < 5; ++i) {
      const int g  = i * 512 + t;      // float4 index 0..2559
      const int fl = g * 4;            // flat float index
      const int p  = g / 320;          // = fl / 1280
      const int r  = fl - p * 1280;
      *(float4*)&lds[HS_OFF + p * 1320 + (r >> 6) * 66 + (r & 63)] = hv[i];
    }
  }
  __syncthreads();   // barrier 1

  // ---------- P2: scores + softmax. wave = pair, halves handle 4 heads ----
  {
    const int p  = w;
    const int m  = lane & 31;
    const int nn = lane >> 5;
    const int mm = (m < 20) ? m : 19;
    const bool act = (m < 20);
    const float* hsrow = &lds[HS_OFF + p * 1320 + mm * 66];
    const float* vb    = &lds[V_OFF + p * 520 + nn * 256];
    float s[4];
#pragma unroll
    for (int it = 0; it < 4; ++it) s[it] = lds[C_OFF + p * 8 + nn * 4 + it];
#pragma unroll 4
    for (int dq = 0; dq < 16; ++dq) {
      const float4 h4 = *(const float4*)&hsrow[dq * 4];
#pragma unroll
      for (int it = 0; it < 4; ++it) {
        const float4 v4 = *(const float4*)&vb[it * 64 + dq * 4];
        s[it] += h4.x * v4.x + h4.y * v4.y + h4.z * v4.z + h4.w * v4.w;
      }
    }
    const int lenp = (int)lds[LEN_OFF + p];
    float at[4];
#pragma unroll
    for (int it = 0; it < 4; ++it) {
      float sv = (act && m < lenp) ? s[it] : NEGV;
      float mx = sv;
#pragma unroll
      for (int o = 16; o; o >>= 1) mx = fmaxf(mx, __shfl_xor(mx, o, 32));
      const float e = act ? __expf(sv - mx) : 0.f;
      float sm = e;
#pragma unroll
      for (int o = 16; o; o >>= 1) sm += __shfl_xor(sm, o, 32);
      at[it] = e / sm;
    }
    if (act)
      *(float4*)&lds[ATT_OFF + p * 200 + m * 10 + nn * 4] =
          make_float4(at[0], at[1], at[2], at[3]);
  }
  // no barrier: P3 reads only this wave's pair (attn, hs, V all pair-local)

  // ---------- P3: wv[p][n][d] = sum_m attn[p][m][n]*hs[p][m][d] ------------
  {
    const int p = w, d = lane;
    float wv[8] = {0.f, 0.f, 0.f, 0.f, 0.f, 0.f, 0.f, 0.f};
    const float* hsp = &lds[HS_OFF + p * 1320];
    const float* atp = &lds[ATT_OFF + p * 200];
#pragma unroll 4
    for (int m = 0; m < 20; ++m) {
      const float h  = hsp[m * 66 + d];
      const float4 a0 = *(const float4*)&atp[m * 10];
      const float4 a1 = *(const float4*)&atp[m * 10 + 4];
      wv[0] += a0.x * h; wv[1] += a0.y * h; wv[2] += a0.z * h; wv[3] += a0.w * h;
      wv[4] += a1.x * h; wv[5] += a1.y * h; wv[6] += a1.z * h; wv[7] += a1.w * h;
    }
    float* vd = &lds[V_OFF + p * 520 + d];   // overwrite V (dead after P2)
#pragma unroll
    for (int n = 0; n < 8; ++n) vd[n * 64] = wv[n];
  }
  __syncthreads();   // barrier 2 (P4a reads all pairs' wv)

  // ---------- P4a: y[p][n][d] = sum_dd wv[p][n*64+dd]*Wf[n*64+dd][d] -------
  {
    const int n = w, d = lane;
    float acc[8] = {0.f, 0.f, 0.f, 0.f, 0.f, 0.f, 0.f, 0.f};
    const float* wfb = &Wf[(n * 64) * 64 + d];
#pragma unroll 4
    for (int ddq = 0; ddq < 16; ++ddq) {
      const float wf0 = wfb[(ddq * 4 + 0) * 64];
      const float wf1 = wfb[(ddq * 4 + 1) * 64];
      const float wf2 = wfb[(ddq * 4 + 2) * 64];
      const float wf3 = wfb[(ddq * 4 + 3) * 64];
#pragma unroll
      for (int p = 0; p < 8; ++p) {
        const float4 v4 = *(const float4*)&lds[V_OFF + p * 520 + n * 64 + ddq * 4];
        acc[p] += v4.x * wf0 + v4.y * wf1 + v4.z * wf2 + v4.w * wf3;
      }
    }
#pragma unroll
    for (int p = 0; p < 8; ++p)
      lds[HS_OFF + p * 528 + n * 66 + d] = acc[p];   // y into dead hs arena
  }
  __syncthreads();   // barrier 3

  // ---------- P4b: out[p][d] = bf[d] + sum_n y[p][n][d] --------------------
  {
    const int p = t >> 6, d = t & 63;
    float o = bf[d];
#pragma unroll
    for (int n = 0; n < 8; ++n) o += lds[HS_OFF + p * 528 + n * 66 + d];
    out[(size_t)pair0 * 64 + t] = o;
  }
}

extern "C" void kernel_launch(void* const* d_in, const int* in_sizes, int n_in,
                              void* d_out, int out_size, void* d_ws, size_t ws_size,
                              hipStream_t stream) {
  const float* ht  = (const float*)d_in[0];
  const float* hs  = (const float*)d_in[1];
  const int*   len = (const int*)d_in[2];
  const float* Wt  = (const float*)d_in[3];
  const float* bt  = (const float*)d_in[4];
  const float* Ws  = (const float*)d_in[5];
  const float* bs  = (const float*)d_in[6];
  const float* Wf  = (const float*)d_in[7];
  const float* bf  = (const float*)d_in[8];
  float* outp = (float*)d_out;
  float* ws   = (float*)d_ws;

  hipLaunchKernelGGL(prep_kernel, dim3(32), dim3(256), 0, stream,
                     Wt, bt, Ws, bs, ws);
  hipLaunchKernelGGL(attn_kernel, dim3(4096), dim3(512), 0, stream,
                     ht, hs, len, Wf, bf, ws, outp);
}

// Round 3
// 235.395 us; speedup vs baseline: 1.3113x; 1.3113x over previous
//
#include <hip/hip_runtime.h>

// dims: S=128, E=256 -> 32768 pairs; H=20, D=64, A=64, NH=8
constexpr float TEMP = 2.5f;    // H / sqrt(A) = 20/8
constexpr float NEGV = -1e9f;

// ---- workspace layout (floats) ----
constexpr int M_OFF = 0;        // M[8][64][64]  (pre-scaled by TEMP)
constexpr int K_OFF = 32768;    // k[8][64]
constexpr int P_OFF = 33280;    // p[8][64]
constexpr int Q_OFF = 33792;    // q[8]

// ---- main-kernel LDS layout (floats) ----  (~40 KB -> 3-4 blocks/CU)
constexpr int V_OFF   = 0;      // V/wv [8 pairs][520]  (4160)
constexpr int ATT_OFF = 4160;   // attn[8][20*10]       (1600)
constexpr int Y_OFF   = 5760;   // y[8 pairs][8][66]    (4224)
constexpr int C_OFF   = 9984;   // c[8 pairs][8 heads]  (64)
constexpr int LEN_OFF = 10048;  // len[8]               (8)
constexpr int LDS_FL  = 10056;  // 40,224 B

// ============================================================
// prep: M[n][dp][d] = sum_a Wt[n][dp][a]*Ws[n][d][a];  k = Ws·bt;
//       p = Wt·bs;  q = bt·bs.  All scaled by TEMP.  (unchanged, verified)
// ============================================================
__global__ __launch_bounds__(256) void prep_kernel(
    const float* __restrict__ Wt, const float* __restrict__ bt,
    const float* __restrict__ Ws, const float* __restrict__ bs,
    float* __restrict__ ws) {
  __shared__ float WsL[64 * 65];
  __shared__ float WtL[16 * 65];
  const int t  = threadIdx.x;
  const int n  = blockIdx.x >> 2;
  const int q  = blockIdx.x & 3;
  const int dp0 = q * 16;
  const float* Wtn = Wt + n * 4096;
  const float* Wsn = Ws + n * 4096;
#pragma unroll
  for (int i = 0; i < 16; ++i) {
    const int idx = i * 256 + t;
    WsL[(idx >> 6) * 65 + (idx & 63)] = Wsn[idx];
  }
#pragma unroll
  for (int i = 0; i < 4; ++i) {
    const int idx = i * 256 + t;
    WtL[(idx >> 6) * 65 + (idx & 63)] = Wtn[dp0 * 64 + idx];
  }
  __syncthreads();
#pragma unroll
  for (int i = 0; i < 4; ++i) {
    const int idx = i * 256 + t;
    const int dpl = idx >> 6, d = idx & 63;
    const float* wtr = &WtL[dpl * 65];
    const float* wsr = &WsL[d * 65];
    float acc = 0.f;
#pragma unroll 8
    for (int a = 0; a < 64; ++a) acc += wtr[a] * wsr[a];
    ws[M_OFF + n * 4096 + (dp0 + dpl) * 64 + d] = acc * TEMP;
  }
  if (q == 0 && t < 64) {
    float acc = 0.f;
#pragma unroll 8
    for (int a = 0; a < 64; ++a) acc += WsL[t * 65 + a] * bt[n * 64 + a];
    ws[K_OFF + n * 64 + t] = acc * TEMP;
  }
  if (t >= 64 && t < 80) {
    const int r = t - 64;
    float acc = 0.f;
#pragma unroll 8
    for (int a = 0; a < 64; ++a) acc += WtL[r * 65 + a] * bs[n * 64 + a];
    ws[P_OFF + n * 64 + dp0 + r] = acc * TEMP;
  }
  if (q == 0 && t == 128) {
    float acc = 0.f;
    for (int a = 0; a < 64; ++a) acc += bt[n * 64 + a] * bs[n * 64 + a];
    ws[Q_OFF + n] = acc * TEMP;
  }
}

// ============================================================
// main: 8 pairs/block, 512 threads (8 waves), grid 4096.
// hs is NOT staged (L2/L3-resident); LDS only for V/attn/y/c.
// ============================================================
__global__ __launch_bounds__(512, 6) void attn_kernel(
    const float* __restrict__ ht_g, const float* __restrict__ hs_g,
    const int* __restrict__ len_g, const float* __restrict__ Wf,
    const float* __restrict__ bf, const float* __restrict__ wsp,
    float* __restrict__ out) {
  __shared__ float lds[LDS_FL];
  const int t    = threadIdx.x;
  const int lane = t & 63;
  const int w    = t >> 6;            // wave id 0..7
  const int pair0 = blockIdx.x * 8;

  if (t < 8) lds[LEN_OFF + t] = (float)len_g[pair0 + t];

  // ---------- V phase: wave w = head n, lane = d, 8 pair-accumulators ------
  // V[p][n][d] = k[n][d] + sum_dp ht[p][dp] * M[n][dp][d]
  {
    const int n = w;
    const int d = lane;
    float acc[8];
    const float kv = wsp[K_OFF + n * 64 + d];
#pragma unroll
    for (int p = 0; p < 8; ++p) acc[p] = kv;
    const float* Mn  = &wsp[M_OFF + n * 4096];
    const float* htb = ht_g + (size_t)pair0 * 64;   // wave-uniform -> s_load
#pragma unroll 8
    for (int dp = 0; dp < 64; ++dp) {
      const float mv = Mn[dp * 64 + d];             // coalesced b32 (L2)
#pragma unroll
      for (int p = 0; p < 8; ++p)
        acc[p] = fmaf(htb[p * 64 + dp], mv, acc[p]);
    }
    float* vp = &lds[V_OFF + n * 64 + d];
#pragma unroll
    for (int p = 0; p < 8; ++p) vp[p * 520] = acc[p];
  }

  // ---------- c[p][n] = q[n] + ht·p[n]  (8 lanes of each wave) ------------
  {
    const int n = w;
    if (lane < 8) {
      const float* htp = ht_g + (size_t)(pair0 + lane) * 64;
      float cacc = wsp[Q_OFF + n];
#pragma unroll 8
      for (int dp = 0; dp < 64; ++dp)
        cacc = fmaf(htp[dp], wsp[P_OFF + n * 64 + dp], cacc);
      lds[C_OFF + lane * 8 + n] = cacc;
    }
  }
  __syncthreads();   // barrier 1: V,c,len visible

  // ---------- P2: scores + softmax. wave = pair, halves handle 4 heads ----
  // hs rows read straight from global (L2/L3-hot).
  {
    const int p  = w;
    const int m  = lane & 31;
    const int nn = lane >> 5;
    const int mm = (m < 20) ? m : 19;
    const bool act = (m < 20);
    const float* hsrow = hs_g + (size_t)(pair0 + p) * 1280 + mm * 64;
    const float* vb    = &lds[V_OFF + p * 520 + nn * 256];
    float s[4];
#pragma unroll
    for (int it = 0; it < 4; ++it) s[it] = lds[C_OFF + p * 8 + nn * 4 + it];
#pragma unroll 4
    for (int dq = 0; dq < 16; ++dq) {
      const float4 h4 = *(const float4*)&hsrow[dq * 4];
#pragma unroll
      for (int it = 0; it < 4; ++it) {
        const float4 v4 = *(const float4*)&vb[it * 64 + dq * 4];
        s[it] += h4.x * v4.x + h4.y * v4.y + h4.z * v4.z + h4.w * v4.w;
      }
    }
    const int lenp = (int)lds[LEN_OFF + p];
    float at[4];
#pragma unroll
    for (int it = 0; it < 4; ++it) {
      float sv = (act && m < lenp) ? s[it] : NEGV;
      float mx = sv;
#pragma unroll
      for (int o = 16; o; o >>= 1) mx = fmaxf(mx, __shfl_xor(mx, o, 32));
      const float e = act ? __expf(sv - mx) : 0.f;
      float sm = e;
#pragma unroll
      for (int o = 16; o; o >>= 1) sm += __shfl_xor(sm, o, 32);
      at[it] = e / sm;
    }
    if (act)
      *(float4*)&lds[ATT_OFF + p * 200 + m * 10 + nn * 4] =
          make_float4(at[0], at[1], at[2], at[3]);
  }
  // no barrier: P3 reads only this wave's pair (attn, V pair-local)

  // ---------- P3: wv[p][n][d] = sum_m attn[p][m][n]*hs[p][m][d] ------------
  // hs read from global, coalesced per lane=d (L2-hot from P2).
  {
    const int p = w, d = lane;
    float wv[8] = {0.f, 0.f, 0.f, 0.f, 0.f, 0.f, 0.f, 0.f};
    const float* hsp = hs_g + (size_t)(pair0 + p) * 1280;
    const float* atp = &lds[ATT_OFF + p * 200];
#pragma unroll 4
    for (int m = 0; m < 20; ++m) {
      const float h  = hsp[m * 64 + d];
      const float4 a0 = *(const float4*)&atp[m * 10];
      const float4 a1 = *(const float4*)&atp[m * 10 + 4];
      wv[0] += a0.x * h; wv[1] += a0.y * h; wv[2] += a0.z * h; wv[3] += a0.w * h;
      wv[4] += a1.x * h; wv[5] += a1.y * h; wv[6] += a1.z * h; wv[7] += a1.w * h;
    }
    float* vd = &lds[V_OFF + p * 520 + d];   // overwrite V (dead after P2)
#pragma unroll
    for (int n = 0; n < 8; ++n) vd[n * 64] = wv[n];
  }
  __syncthreads();   // barrier 2 (P4a reads all pairs' wv)

  // ---------- P4a: y[p][n][d] = sum_dd wv[p][n*64+dd]*Wf[n*64+dd][d] -------
  {
    const int n = w, d = lane;
    float acc[8] = {0.f, 0.f, 0.f, 0.f, 0.f, 0.f, 0.f, 0.f};
    const float* wfb = &Wf[(n * 64) * 64 + d];
#pragma unroll 4
    for (int ddq = 0; ddq < 16; ++ddq) {
      const float wf0 = wfb[(ddq * 4 + 0) * 64];
      const float wf1 = wfb[(ddq * 4 + 1) * 64];
      const float wf2 = wfb[(ddq * 4 + 2) * 64];
      const float wf3 = wfb[(ddq * 4 + 3) * 64];
#pragma unroll
      for (int p = 0; p < 8; ++p) {
        const float4 v4 = *(const float4*)&lds[V_OFF + p * 520 + n * 64 + ddq * 4];
        acc[p] += v4.x * wf0 + v4.y * wf1 + v4.z * wf2 + v4.w * wf3;
      }
    }
#pragma unroll
    for (int p = 0; p < 8; ++p)
      lds[Y_OFF + p * 528 + n * 66 + d] = acc[p];
  }
  __syncthreads();   // barrier 3

  // ---------- P4b: out[p][d] = bf[d] + sum_n y[p][n][d] --------------------
  {
    const int p = t >> 6, d = t & 63;
    float o = bf[d];
#pragma unroll
    for (int n = 0; n < 8; ++n) o += lds[Y_OFF + p * 528 + n * 66 + d];
    out[(size_t)pair0 * 64 + t] = o;
  }
}

extern "C" void kernel_launch(void* const* d_in, const int* in_sizes, int n_in,
                              void* d_out, int out_size, void* d_ws, size_t ws_size,
                              hipStream_t stream) {
  const float* ht  = (const float*)d_in[0];
  const float* hs  = (const float*)d_in[1];
  const int*   len = (const int*)d_in[2];
  const float* Wt  = (const float*)d_in[3];
  const float* bt  = (const float*)d_in[4];
  const float* Ws  = (const float*)d_in[5];
  const float* bs  = (const float*)d_in[6];
  const float* Wf  = (const float*)d_in[7];
  const float* bf  = (const float*)d_in[8];
  float* outp = (float*)d_out;
  float* ws   = (float*)d_ws;

  hipLaunchKernelGGL(prep_kernel, dim3(32), dim3(256), 0, stream,
                     Wt, bt, Ws, bs, ws);
  hipLaunchKernelGGL(attn_kernel, dim3(4096), dim3(512), 0, stream,
                     ht, hs, len, Wf, bf, ws, outp);
}